// Round 4
// baseline (339.837 us; speedup 1.0000x reference)
//
#include <hip/hip_runtime.h>
#include <stdint.h>

#define N_TOK 2048
#define DDIM 1024
#define HDIM 4096
#define NEXP 8
#define BM 128
#define MAXT 24
#define PADCAP 3072

// ctrl block layout (int offsets into d_ws)
#define C_COUNTS 0
#define C_CURSOR 8
#define C_PADOFF 16
#define C_TILECNT 25
#define C_TILE_E 32
#define C_TILE_M0 56
#define C_TILE_ROWS 80
#define C_EXPERT 128
#define C_PERM 2176            // 3072 ints

#define XG_OFF 32768                       // bf16 [PADCAP][DDIM]  = 6.29 MB
#define HG_OFF (XG_OFF + PADCAP*DDIM*2)    // bf16 [PADCAP][HDIM]  = 25.2 MB

typedef float f32x4 __attribute__((ext_vector_type(4)));
typedef short s16x8 __attribute__((ext_vector_type(8)));
typedef unsigned int u32;
typedef unsigned short u16;

__device__ __forceinline__ u16 f2bf(float f){
  u32 u = __float_as_uint(f);
  u += 0x7fffu + ((u >> 16) & 1u);   // RNE
  return (u16)(u >> 16);
}

__device__ __forceinline__ u32 pkbf(float a, float b){   // {lo16=bf(a), hi16=bf(b)}
  u32 r; asm("v_cvt_pk_bf16_f32 %0, %1, %2" : "=v"(r) : "v"(a), "v"(b)); return r;
}

// ---------------- gating: fp32 logits, argmax (first-max tie rule), counts ---
__global__ __launch_bounds__(256) void gate_kern(
    const float* __restrict__ x, const float* __restrict__ gw,
    const float* __restrict__ gb, int* __restrict__ ctrl)
{
  const int wv = threadIdx.x >> 6, l = threadIdx.x & 63;
  const int n = blockIdx.x * 4 + wv;            // one wave per token
  const float* xr = x + (size_t)n * DDIM;
  float acc[NEXP];
  #pragma unroll
  for (int e = 0; e < NEXP; e++) acc[e] = 0.f;
  #pragma unroll 4
  for (int i = 0; i < DDIM/64; i++){
    int k = i*64 + l;
    float xv = xr[k];
    const float* g = gw + (size_t)k * NEXP;
    #pragma unroll
    for (int e = 0; e < NEXP; e++) acc[e] = fmaf(xv, g[e], acc[e]);
  }
  #pragma unroll
  for (int e = 0; e < NEXP; e++){
    #pragma unroll
    for (int off = 32; off > 0; off >>= 1) acc[e] += __shfl_xor(acc[e], off);
  }
  if (l == 0){
    float best = acc[0] + gb[0]; int bi = 0;
    #pragma unroll
    for (int e = 1; e < NEXP; e++){
      float v = acc[e] + gb[e];
      if (v > best){ best = v; bi = e; }        // strict > keeps first index
    }
    ctrl[C_EXPERT + n] = bi;
    atomicAdd(&ctrl[C_COUNTS + bi], 1);
  }
}

// ------------- setup: aux loss, padded offsets, tile table, perm init --------
__global__ void setup_kern(int* __restrict__ ctrl, float* __restrict__ aux_out)
{
  const int t = threadIdx.x;
  for (int i = t; i < PADCAP; i += 256) ctrl[C_PERM + i] = -1;
  if (t == 0){
    int off = 0, tc = 0;
    float aux = 0.f;
    for (int e = 0; e < NEXP; e++){
      int c = ctrl[C_COUNTS + e];
      ctrl[C_PADOFF + e] = off;
      ctrl[C_CURSOR + e] = off;
      int nt = (c + BM - 1) / BM;
      for (int j = 0; j < nt; j++){
        ctrl[C_TILE_E   + tc] = e;
        ctrl[C_TILE_M0  + tc] = off + j*BM;
        ctrl[C_TILE_ROWS+ tc] = min(BM, c - j*BM);
        tc++;
      }
      off += nt * BM;
      float fr = (float)c * (1.f/(float)N_TOK);
      float d = fr - 1.f/(float)NEXP;
      aux += d*d;
    }
    ctrl[C_TILECNT] = tc;
    *aux_out = aux * (1.f/(float)NEXP);
  }
}

// ------------------------- scatter tokens into grouped slots -----------------
__global__ __launch_bounds__(256) void scatter_kern(int* __restrict__ ctrl)
{
  const int n = blockIdx.x * 256 + threadIdx.x;
  const int e = ctrl[C_EXPERT + n];
  const int pos = atomicAdd(&ctrl[C_CURSOR + e], 1);
  ctrl[C_PERM + pos] = n;
}

// ------------------ gather + f32->bf16 convert of x into Xg ------------------
__global__ __launch_bounds__(256) void xg_kern(
    const float* __restrict__ x, const int* __restrict__ ctrl,
    u16* __restrict__ Xg)
{
  const int slot = blockIdx.x, t = threadIdx.x;
  const int tok = ctrl[C_PERM + slot];
  ushort4 o;
  if (tok >= 0){
    f32x4 v = *(const f32x4*)(x + (size_t)tok*DDIM + t*4);
    o.x = f2bf(v.x); o.y = f2bf(v.y); o.z = f2bf(v.z); o.w = f2bf(v.w);
  } else { o.x = 0; o.y = 0; o.z = 0; o.w = 0; }
  *(ushort4*)(Xg + (size_t)slot*DDIM + t*4) = o;
}

// --------------------------- the two FFN GEMMs -------------------------------
// MODE 1: Hg = gelu(Xg @ w1[e] + b1[e])   K=1024, N=4096, BN=64
// MODE 2: out[tok] += Hg @ w2[e] + b2[e]  K=4096, N=1024, BN=64,
//                                          split-K x4 (blockIdx.z), fp32 atomics
//
// ZERO-LDS design. Every previous round (glds staging, counted-vmcnt,
// read-side transpose, split-K occupancy) converged to ~2000 cy per
// K-iteration per CU -> the shared per-CU LDS pipe was the invariant cost.
// Here both operands load fragment-direct from global, fully coalesced:
//   A-frag: 16 rows x 16B, lanes (llo,lhi) -> 16 full 64B lines per wave-op.
//   B-frag: 8 k-rows (stride NN) x 16 cols fp32 -> full 64B lines; cvt_pk
//           in-register (same value pairs as before -> bit-identical math).
// No __shared__, no barriers; 1-deep register double-buffer + 12 waves/CU
// TLP hides L2/L3 latency. Redundant reads (wave pairs) go to idle L2/L3.
template<int MODE>
__global__ __launch_bounds__(256, 3) void moe_gemm(
    const u16* __restrict__ Ag, const float* __restrict__ W,
    const float* __restrict__ bias, u16* __restrict__ Hg,
    float* __restrict__ outp, const int* __restrict__ ctrl)
{
  constexpr int K    = (MODE==1) ? DDIM : HDIM;   // full reduction dim
  constexpr int NN   = (MODE==1) ? HDIM : DDIM;   // output dim
  constexpr int KS   = (MODE==1) ? 1 : 4;         // split-K factor
  constexpr int KLOC = K / KS;                    // 1024 / 1024
  constexpr int BN   = 64;
  constexpr int BK   = 32;
  constexpr int NF   = BN / 32;                   // 2 n-frags per wave
  constexpr int NT   = KLOC / BK;                 // 32 / 32

  const int by = blockIdx.y;
  if (by >= ctrl[C_TILECNT]) return;
  const int e    = ctrl[C_TILE_E + by];
  const int m0   = ctrl[C_TILE_M0 + by];
  const int rows = ctrl[C_TILE_ROWS + by];
  const int n0   = blockIdx.x * BN;
  const int kb   = (MODE==1) ? 0 : blockIdx.z * KLOC;

  const int tid = threadIdx.x;
  const int w = tid >> 6, l = tid & 63;
  const int wr = w >> 1, wc = w & 1;
  const int lhi = l >> 4, llo = l & 15;

  f32x4 acc[4][NF];
  #pragma unroll
  for (int mf = 0; mf < 4; mf++)
    #pragma unroll
    for (int nf = 0; nf < NF; nf++) acc[mf][nf] = (f32x4){0.f,0.f,0.f,0.f};

  // A: this lane's 4 row-bases (one per m-frag), 16B granules along k
  const u16* Arow = Ag + (size_t)(m0 + wr*64 + llo) * K + lhi*8;
  // B: this lane's column base; k walks stride NN
  const float* Wc = W + (size_t)e * K * NN + n0 + wc*32 + llo;

  s16x8 af0[4], af1[4];
  float bw0[NF*8], bw1[NF*8];

#define LOADA(AF, k0) { \
    _Pragma("unroll") \
    for (int mf = 0; mf < 4; mf++) \
      AF[mf] = *(const s16x8*)(Arow + (size_t)mf*16*K + (k0)); }

#define LOADB(BW, k0) { \
    _Pragma("unroll") \
    for (int nf = 0; nf < NF; nf++){ \
      const float* wp = Wc + (size_t)((k0) + lhi*8) * NN + nf*16; \
      _Pragma("unroll") \
      for (int j = 0; j < 8; j++) \
        BW[nf*8+j] = wp[(size_t)j * NN]; } }

#define COMP(AF, BW) { \
    _Pragma("unroll") \
    for (int nf = 0; nf < NF; nf++){ \
      union { u32 u[4]; s16x8 v; } bb_; \
      bb_.u[0] = pkbf(BW[nf*8+0], BW[nf*8+1]); \
      bb_.u[1] = pkbf(BW[nf*8+2], BW[nf*8+3]); \
      bb_.u[2] = pkbf(BW[nf*8+4], BW[nf*8+5]); \
      bb_.u[3] = pkbf(BW[nf*8+6], BW[nf*8+7]); \
      _Pragma("unroll") \
      for (int mf = 0; mf < 4; mf++) \
        acc[mf][nf] = __builtin_amdgcn_mfma_f32_16x16x32_bf16(AF[mf], bb_.v, acc[mf][nf], 0, 0, 0); } }

  LOADA(af0, kb);
  LOADB(bw0, kb);

  #pragma unroll 1
  for (int t = 0; t < NT; t += 2){
    if (t+1 < NT){ LOADA(af1, kb + (t+1)*BK); LOADB(bw1, kb + (t+1)*BK); }
    COMP(af0, bw0);
    if (t+2 < NT){ LOADA(af0, kb + (t+2)*BK); LOADB(bw0, kb + (t+2)*BK); }
    if (t+1 < NT){ COMP(af1, bw1); }
  }

  if constexpr (MODE == 1){
    const float* bp = bias + (size_t)e*NN + n0;
    #pragma unroll
    for (int nf = 0; nf < NF; nf++){
      const int cl = wc*32 + nf*16 + llo;
      const float bb = bp[cl];
      #pragma unroll
      for (int mf = 0; mf < 4; mf++){
        #pragma unroll
        for (int r = 0; r < 4; r++){
          const int rl = wr*64 + mf*16 + lhi*4 + r;
          float vv = acc[mf][nf][r] + bb;
          float gel = 0.5f * vv * (1.0f + erff(vv * 0.70710678118f)); // exact gelu
          Hg[(size_t)(m0+rl)*NN + n0 + cl] = f2bf(gel);
        }
      }
    }
  } else {
    const float* bp = bias + (size_t)e*NN + n0;
    const bool addb = (blockIdx.z == 0);
    #pragma unroll
    for (int mf = 0; mf < 4; mf++){
      #pragma unroll
      for (int r = 0; r < 4; r++){
        const int rl = wr*64 + mf*16 + lhi*4 + r;
        if (rl < rows){
          const int tok = ctrl[C_PERM + m0 + rl];
          #pragma unroll
          for (int nf = 0; nf < NF; nf++){
            const int cl = wc*32 + nf*16 + llo;
            float v = acc[mf][nf][r] + (addb ? bp[cl] : 0.f);
            atomicAdd(&outp[(size_t)tok*DDIM + n0 + cl], v);
          }
        }
      }
    }
  }
#undef LOADA
#undef LOADB
#undef COMP
}

extern "C" void kernel_launch(void* const* d_in, const int* in_sizes, int n_in,
                              void* d_out, int out_size, void* d_ws, size_t ws_size,
                              hipStream_t stream)
{
  (void)in_sizes; (void)n_in; (void)out_size; (void)ws_size;
  const float* x  = (const float*)d_in[0];
  const float* gw = (const float*)d_in[1];
  const float* gb = (const float*)d_in[2];
  const float* w1 = (const float*)d_in[3];
  const float* b1 = (const float*)d_in[4];
  const float* w2 = (const float*)d_in[5];
  const float* b2 = (const float*)d_in[6];
  float* out = (float*)d_out;
  char* ws = (char*)d_ws;
  int* ctrl = (int*)ws;
  u16* Xg = (u16*)(ws + XG_OFF);
  u16* Hg = (u16*)(ws + HG_OFF);

  hipMemsetAsync(ctrl, 0, 64, stream);                       // counts
  hipMemsetAsync(out, 0, (size_t)N_TOK*DDIM*4, stream);      // split-K accum base
  gate_kern<<<N_TOK/4, 256, 0, stream>>>(x, gw, gb, ctrl);
  setup_kern<<<1, 256, 0, stream>>>(ctrl, out + (size_t)N_TOK*DDIM);
  scatter_kern<<<N_TOK/256, 256, 0, stream>>>(ctrl);
  xg_kern<<<PADCAP, 256, 0, stream>>>(x, ctrl, Xg);
  moe_gemm<1><<<dim3(HDIM/64, MAXT),    256, 0, stream>>>(Xg, w1, b1, Hg, nullptr, ctrl);
  moe_gemm<2><<<dim3(DDIM/64, MAXT, 4), 256, 0, stream>>>(Hg, w2, b2, nullptr, out, ctrl);
}

// Round 5
// 232.751 us; speedup vs baseline: 1.4601x; 1.4601x over previous
//
#include <hip/hip_runtime.h>
#include <stdint.h>

#define N_TOK 2048
#define DDIM 1024
#define HDIM 4096
#define NEXP 8
#define BM 128
#define MAXT 24
#define PADCAP 3072

// ctrl block layout (int offsets into d_ws)
#define C_COUNTS 0
#define C_CURSOR 8
#define C_PADOFF 16
#define C_TILECNT 25
#define C_TILE_E 32
#define C_TILE_M0 56
#define C_TILE_ROWS 80
#define C_EXPERT 128
#define C_PERM 2176            // 3072 ints

#define XG_OFF 32768                       // bf16 [PADCAP][DDIM]  = 6.29 MB
#define HG_OFF (XG_OFF + PADCAP*DDIM*2)    // bf16 [PADCAP][HDIM]  = 25.2 MB

typedef float f32x4 __attribute__((ext_vector_type(4)));
typedef short s16x8 __attribute__((ext_vector_type(8)));
typedef unsigned int u32;
typedef unsigned short u16;

__device__ __forceinline__ u16 f2bf(float f){
  u32 u = __float_as_uint(f);
  u += 0x7fffu + ((u >> 16) & 1u);   // RNE
  return (u16)(u >> 16);
}

__device__ __forceinline__ u32 pkbf(float a, float b){   // {lo16=bf(a), hi16=bf(b)}
  u32 r; asm("v_cvt_pk_bf16_f32 %0, %1, %2" : "=v"(r) : "v"(a), "v"(b)); return r;
}

__device__ __forceinline__ void gl_lds16(const void* g, void* l){
  __builtin_amdgcn_global_load_lds((const __attribute__((address_space(1))) u32*)g,
                                   (__attribute__((address_space(3))) u32*)l, 16, 0, 0);
}

// ---------------- gating: fp32 logits, argmax (first-max tie rule), counts ---
__global__ __launch_bounds__(256) void gate_kern(
    const float* __restrict__ x, const float* __restrict__ gw,
    const float* __restrict__ gb, int* __restrict__ ctrl)
{
  const int wv = threadIdx.x >> 6, l = threadIdx.x & 63;
  const int n = blockIdx.x * 4 + wv;            // one wave per token
  const float* xr = x + (size_t)n * DDIM;
  float acc[NEXP];
  #pragma unroll
  for (int e = 0; e < NEXP; e++) acc[e] = 0.f;
  #pragma unroll 4
  for (int i = 0; i < DDIM/64; i++){
    int k = i*64 + l;
    float xv = xr[k];
    const float* g = gw + (size_t)k * NEXP;
    #pragma unroll
    for (int e = 0; e < NEXP; e++) acc[e] = fmaf(xv, g[e], acc[e]);
  }
  #pragma unroll
  for (int e = 0; e < NEXP; e++){
    #pragma unroll
    for (int off = 32; off > 0; off >>= 1) acc[e] += __shfl_xor(acc[e], off);
  }
  if (l == 0){
    float best = acc[0] + gb[0]; int bi = 0;
    #pragma unroll
    for (int e = 1; e < NEXP; e++){
      float v = acc[e] + gb[e];
      if (v > best){ best = v; bi = e; }        // strict > keeps first index
    }
    ctrl[C_EXPERT + n] = bi;
    atomicAdd(&ctrl[C_COUNTS + bi], 1);
  }
}

// ------------- setup: aux loss, padded offsets, tile table, perm init --------
__global__ void setup_kern(int* __restrict__ ctrl, float* __restrict__ aux_out)
{
  const int t = threadIdx.x;
  for (int i = t; i < PADCAP; i += 256) ctrl[C_PERM + i] = -1;
  if (t == 0){
    int off = 0, tc = 0;
    float aux = 0.f;
    for (int e = 0; e < NEXP; e++){
      int c = ctrl[C_COUNTS + e];
      ctrl[C_PADOFF + e] = off;
      ctrl[C_CURSOR + e] = off;
      int nt = (c + BM - 1) / BM;
      for (int j = 0; j < nt; j++){
        ctrl[C_TILE_E   + tc] = e;
        ctrl[C_TILE_M0  + tc] = off + j*BM;
        ctrl[C_TILE_ROWS+ tc] = min(BM, c - j*BM);
        tc++;
      }
      off += nt * BM;
      float fr = (float)c * (1.f/(float)N_TOK);
      float d = fr - 1.f/(float)NEXP;
      aux += d*d;
    }
    ctrl[C_TILECNT] = tc;
    *aux_out = aux * (1.f/(float)NEXP);
  }
}

// ------------------------- scatter tokens into grouped slots -----------------
__global__ __launch_bounds__(256) void scatter_kern(int* __restrict__ ctrl)
{
  const int n = blockIdx.x * 256 + threadIdx.x;
  const int e = ctrl[C_EXPERT + n];
  const int pos = atomicAdd(&ctrl[C_CURSOR + e], 1);
  ctrl[C_PERM + pos] = n;
}

// ------------------ gather + f32->bf16 convert of x into Xg ------------------
__global__ __launch_bounds__(256) void xg_kern(
    const float* __restrict__ x, const int* __restrict__ ctrl,
    u16* __restrict__ Xg)
{
  const int slot = blockIdx.x, t = threadIdx.x;
  const int tok = ctrl[C_PERM + slot];
  ushort4 o;
  if (tok >= 0){
    f32x4 v = *(const f32x4*)(x + (size_t)tok*DDIM + t*4);
    o.x = f2bf(v.x); o.y = f2bf(v.y); o.z = f2bf(v.z); o.w = f2bf(v.w);
  } else { o.x = 0; o.y = 0; o.z = 0; o.w = 0; }
  *(ushort4*)(Xg + (size_t)slot*DDIM + t*4) = o;
}

// --------------------------- the two FFN GEMMs -------------------------------
// MODE 1: Hg = gelu(Xg @ w1[e] + b1[e])   K=1024, N=4096, BN=64, BK=32
// MODE 2: out[tok] += Hg @ w2[e] + b2[e]  K=4096, N=1024, BN=64, BK=32,
//                                          split-K x4 (blockIdx.z), fp32 atomics
//
// Composite of the three best-measured pieces:
//  - R2 inner loop: full-width global_load_lds staging for BOTH operands,
//    W (fp32) k-transposed on the LDS-read side (conflict-free).
//  - R3 geometry: BN=64/BK=32, ~1024-1088 real blocks per dispatch.
//  - R1 schedule: triple-buffer counted-vmcnt pipeline. Per iter each thread
//    issues 4 glds (A:2 + B:2); vmcnt(4) retires exactly tile t+1's loads;
//    tile t+2's 4 stay in flight ACROSS the raw s_barrier (never drain to 0).
//    Safety: each wave retires its own glds before the barrier, so after the
//    barrier every wave's slice of buffer t+1 is visible -> compute(t+1) ok.
// Per CU: 3 blocks x 4 waves x ~4KB continuously outstanding ~ 48 KB >> the
// ~9 KB Little's-law requirement for 6 TB/s.
template<int MODE>
__global__ __launch_bounds__(256, 3) void moe_gemm(
    const u16* __restrict__ Ag, const float* __restrict__ W,
    const float* __restrict__ bias, u16* __restrict__ Hg,
    float* __restrict__ outp, const int* __restrict__ ctrl)
{
  constexpr int K    = (MODE==1) ? DDIM : HDIM;   // full reduction dim
  constexpr int NN   = (MODE==1) ? HDIM : DDIM;   // output dim
  constexpr int KS   = (MODE==1) ? 1 : 4;         // split-K factor
  constexpr int KLOC = K / KS;                    // 1024 / 1024
  constexpr int BN   = 64;
  constexpr int BK   = 32;
  constexpr int NF   = BN / 32;                   // 2 n-frags per wave
  constexpr int CPR  = BK / 8;                    // A 16B-chunks per row: 4
  constexpr int AVM  = (BM*BK)/(256*8);           // A glds per thread: 2
  constexpr int BCPR = BN / 4;                    // W 16B-chunks per row: 16
  constexpr int BVM  = (BK*BN)/(256*4);           // W glds per thread: 2
  constexpr int NT   = KLOC / BK;                 // 32

  const int by = blockIdx.y;
  if (by >= ctrl[C_TILECNT]) return;
  const int e    = ctrl[C_TILE_E + by];
  const int m0   = ctrl[C_TILE_M0 + by];
  const int rows = ctrl[C_TILE_ROWS + by];
  const int n0   = blockIdx.x * BN;
  const int kb   = (MODE==1) ? 0 : blockIdx.z * KLOC;

  const int tid = threadIdx.x;
  const int w = tid >> 6, l = tid & 63;
  const int wr = w >> 1, wc = w & 1;
  const int lhi = l >> 4, llo = l & 15;

  __shared__ __align__(16) u16   As[3][BM*BK];   // bf16 A tile, 3 x 8 KB
  __shared__ __align__(16) float Bs[3][BK*BN];   // fp32 W tile, 3 x 8 KB
  __shared__ int perm_s[BM];

  if constexpr (MODE == 2){
    if (tid < BM) perm_s[tid] = ctrl[C_PERM + m0 + tid];
  }

  f32x4 acc[4][NF];
  #pragma unroll
  for (int mf = 0; mf < 4; mf++)
    #pragma unroll
    for (int nf = 0; nf < NF; nf++) acc[mf][nf] = (f32x4){0.f,0.f,0.f,0.f};

  const u16* Abase = Ag + (size_t)m0 * K;
  // A staging: 2 chunks of 16B/thread; source pre-swizzled so that LDS slot
  // (row, c) holds global chunk c ^ SWA(row), SWA(r) = (r&3) ^ (((r>>2)&1)<<1)
  // (second XOR bit breaks the previous 4-way read conflict down to 2-way).
  int arow[AVM], apos[AVM];
  #pragma unroll
  for (int i = 0; i < AVM; i++){
    int f = i*256 + tid;
    arow[i] = f / CPR;
    apos[i] = (f & (CPR-1)) ^ (arow[i] & (CPR-1)) ^ (((arow[i] >> 2) & 1) << 1);
  }
  // W staging: LDS slot (r,c) holds global chunk c ^ SWB(r),
  // SWB(r) = ((r>>3)&1)<<2  (flips chunk bit2 for odd k-octets)
  const float* Wb = W + (size_t)e * K * NN + n0;
  int brow[BVM], bpos[BVM];
  #pragma unroll
  for (int i = 0; i < BVM; i++){
    int f = i*256 + tid;
    brow[i] = f / BCPR;
    bpos[i] = (f % BCPR) ^ (((brow[i] >> 3) & 1) << 2);
  }

  const int col0 = wc*(BN/2) + llo;     // this lane's base output column
  const int bswz = (lhi & 1) << 2;      // read-side chunk swizzle (matches SWB)

#define WAITV(N) asm volatile("s_waitcnt vmcnt(" #N ")" ::: "memory")
#define PIPE_BAR() do { asm volatile("s_waitcnt lgkmcnt(0)" ::: "memory"); \
    __builtin_amdgcn_sched_barrier(0); \
    __builtin_amdgcn_s_barrier(); \
    __builtin_amdgcn_sched_barrier(0); } while(0)

#define STAGE_A(buf, k0) { \
    u16* ad = &As[buf][(w*64)*8]; \
    _Pragma("unroll") \
    for (int i = 0; i < AVM; i++) \
      gl_lds16(Abase + (size_t)arow[i]*K + (k0) + apos[i]*8, ad + i*256*8); }

#define STAGE_B(buf, k0) { \
    float* bd = &Bs[buf][(w*64)*4]; \
    _Pragma("unroll") \
    for (int i = 0; i < BVM; i++) \
      gl_lds16(Wb + (size_t)((k0) + brow[i])*NN + bpos[i]*4, bd + i*256*4); }

#define COMPUTE(buf) { \
    s16x8 a[4]; \
    _Pragma("unroll") \
    for (int mf = 0; mf < 4; mf++){ \
      int row = wr*64 + mf*16 + llo; \
      int pos = (lhi ^ (row & (CPR-1))) ^ (((row >> 2) & 1) << 1); \
      a[mf] = *(const s16x8*)&As[buf][row*BK + pos*8]; } \
    __builtin_amdgcn_s_setprio(1); \
    _Pragma("unroll") \
    for (int nf = 0; nf < NF; nf++){ \
      const int col = col0 + nf*16; \
      const float* bp_ = &Bs[buf][(lhi*8)*BN + \
                                  ((((col) >> 2) ^ bswz) << 2) + ((col) & 3)]; \
      union { u32 u[4]; s16x8 v; } bb_; \
      bb_.u[0] = pkbf(bp_[0*BN], bp_[1*BN]); \
      bb_.u[1] = pkbf(bp_[2*BN], bp_[3*BN]); \
      bb_.u[2] = pkbf(bp_[4*BN], bp_[5*BN]); \
      bb_.u[3] = pkbf(bp_[6*BN], bp_[7*BN]); \
      _Pragma("unroll") \
      for (int mf = 0; mf < 4; mf++) \
        acc[mf][nf] = __builtin_amdgcn_mfma_f32_16x16x32_bf16(a[mf], bb_.v, acc[mf][nf], 0, 0, 0); \
    } \
    __builtin_amdgcn_s_setprio(0); }

  // prologue: tiles 0 and 1 in flight; retire tile 0; barrier (covers perm_s)
  STAGE_A(0, kb);
  STAGE_B(0, kb);
  STAGE_A(1, kb + BK);
  STAGE_B(1, kb + BK);
  WAITV(4);                 // tile 0 landed; tile 1's 4 glds stay in flight
  PIPE_BAR();

  int cbuf = 0, sbuf = 2;
  #pragma unroll 1
  for (int t = 0; t < NT; t++){
    if (t+2 < NT){
      STAGE_A(sbuf, kb + (t+2)*BK);
      STAGE_B(sbuf, kb + (t+2)*BK);
    }
    COMPUTE(cbuf);
    if (t+2 < NT){ WAITV(4); } else { WAITV(0); }
    PIPE_BAR();
    cbuf = (cbuf==2) ? 0 : cbuf+1;
    sbuf = (sbuf==2) ? 0 : sbuf+1;
  }

  if constexpr (MODE == 1){
    const float* bp = bias + (size_t)e*NN + n0;
    #pragma unroll
    for (int nf = 0; nf < NF; nf++){
      const int cl = wc*(BN/2) + nf*16 + llo;
      const float bb = bp[cl];
      #pragma unroll
      for (int mf = 0; mf < 4; mf++){
        #pragma unroll
        for (int r = 0; r < 4; r++){
          const int rl = wr*64 + mf*16 + lhi*4 + r;
          float vv = acc[mf][nf][r] + bb;
          float gel = 0.5f * vv * (1.0f + erff(vv * 0.70710678118f)); // exact gelu
          Hg[(size_t)(m0+rl)*NN + n0 + cl] = f2bf(gel);
        }
      }
    }
  } else {
    const float* bp = bias + (size_t)e*NN + n0;
    const bool addb = (blockIdx.z == 0);
    #pragma unroll
    for (int mf = 0; mf < 4; mf++){
      #pragma unroll
      for (int r = 0; r < 4; r++){
        const int rl = wr*64 + mf*16 + lhi*4 + r;
        if (rl < rows){
          const int tok = perm_s[rl];
          #pragma unroll
          for (int nf = 0; nf < NF; nf++){
            const int cl = wc*(BN/2) + nf*16 + llo;
            float v = acc[mf][nf][r] + (addb ? bp[cl] : 0.f);
            atomicAdd(&outp[(size_t)tok*DDIM + n0 + cl], v);
          }
        }
      }
    }
  }
#undef WAITV
#undef PIPE_BAR
#undef STAGE_A
#undef STAGE_B
#undef COMPUTE
}

extern "C" void kernel_launch(void* const* d_in, const int* in_sizes, int n_in,
                              void* d_out, int out_size, void* d_ws, size_t ws_size,
                              hipStream_t stream)
{
  (void)in_sizes; (void)n_in; (void)out_size; (void)ws_size;
  const float* x  = (const float*)d_in[0];
  const float* gw = (const float*)d_in[1];
  const float* gb = (const float*)d_in[2];
  const float* w1 = (const float*)d_in[3];
  const float* b1 = (const float*)d_in[4];
  const float* w2 = (const float*)d_in[5];
  const float* b2 = (const float*)d_in[6];
  float* out = (float*)d_out;
  char* ws = (char*)d_ws;
  int* ctrl = (int*)ws;
  u16* Xg = (u16*)(ws + XG_OFF);
  u16* Hg = (u16*)(ws + HG_OFF);

  hipMemsetAsync(ctrl, 0, 64, stream);                       // counts
  hipMemsetAsync(out, 0, (size_t)N_TOK*DDIM*4, stream);      // split-K accum base
  gate_kern<<<N_TOK/4, 256, 0, stream>>>(x, gw, gb, ctrl);
  setup_kern<<<1, 256, 0, stream>>>(ctrl, out + (size_t)N_TOK*DDIM);
  scatter_kern<<<N_TOK/256, 256, 0, stream>>>(ctrl);
  xg_kern<<<PADCAP, 256, 0, stream>>>(x, ctrl, Xg);
  moe_gemm<1><<<dim3(HDIM/64, MAXT),    256, 0, stream>>>(Xg, w1, b1, Hg, nullptr, ctrl);
  moe_gemm<2><<<dim3(DDIM/64, MAXT, 4), 256, 0, stream>>>(Hg, w2, b2, nullptr, out, ctrl);
}

// Round 6
// 216.354 us; speedup vs baseline: 1.5708x; 1.0758x over previous
//
#include <hip/hip_runtime.h>
#include <stdint.h>

#define N_TOK 2048
#define DDIM 1024
#define HDIM 4096
#define NEXP 8
#define BM 256
#define MAXT 16
#define ACAP 2560              // Xg/Hg rows: 2048 real + 512 overrun slack

// ctrl block layout (int offsets into d_ws)
#define C_COUNTS 0
#define C_CURSOR 8
#define C_PADOFF 16
#define C_TILECNT 25
#define C_TILE_E 32
#define C_TILE_M0 56
#define C_TILE_ROWS 80
#define C_EXPERT 128
#define C_PERM 2176            // 3072 ints

#define XG_OFF 32768                       // bf16 [ACAP][DDIM]
#define HG_OFF (XG_OFF + ACAP*DDIM*2)      // bf16 [ACAP][HDIM]

typedef float f32x4 __attribute__((ext_vector_type(4)));
typedef short s16x8 __attribute__((ext_vector_type(8)));
typedef unsigned int u32;
typedef u32 u32x2 __attribute__((ext_vector_type(2)));
typedef unsigned short u16;

__device__ __forceinline__ u16 f2bf(float f){
  u32 u = __float_as_uint(f);
  u += 0x7fffu + ((u >> 16) & 1u);   // RNE
  return (u16)(u >> 16);
}

__device__ __forceinline__ u32 pkbf(float a, float b){   // {lo16=bf(a), hi16=bf(b)}
  u32 r; asm("v_cvt_pk_bf16_f32 %0, %1, %2" : "=v"(r) : "v"(a), "v"(b)); return r;
}

__device__ __forceinline__ void gl_lds16(const void* g, void* l){
  __builtin_amdgcn_global_load_lds((const __attribute__((address_space(1))) u32*)g,
                                   (__attribute__((address_space(3))) u32*)l, 16, 0, 0);
}

// ---------------- gating: fp32 logits, argmax (first-max tie rule), counts ---
__global__ __launch_bounds__(256) void gate_kern(
    const float* __restrict__ x, const float* __restrict__ gw,
    const float* __restrict__ gb, int* __restrict__ ctrl)
{
  const int wv = threadIdx.x >> 6, l = threadIdx.x & 63;
  const int n = blockIdx.x * 4 + wv;            // one wave per token
  const float* xr = x + (size_t)n * DDIM;
  float acc[NEXP];
  #pragma unroll
  for (int e = 0; e < NEXP; e++) acc[e] = 0.f;
  #pragma unroll 4
  for (int i = 0; i < DDIM/64; i++){
    int k = i*64 + l;
    float xv = xr[k];
    const float* g = gw + (size_t)k * NEXP;
    #pragma unroll
    for (int e = 0; e < NEXP; e++) acc[e] = fmaf(xv, g[e], acc[e]);
  }
  #pragma unroll
  for (int e = 0; e < NEXP; e++){
    #pragma unroll
    for (int off = 32; off > 0; off >>= 1) acc[e] += __shfl_xor(acc[e], off);
  }
  if (l == 0){
    float best = acc[0] + gb[0]; int bi = 0;
    #pragma unroll
    for (int e = 1; e < NEXP; e++){
      float v = acc[e] + gb[e];
      if (v > best){ best = v; bi = e; }        // strict > keeps first index
    }
    ctrl[C_EXPERT + n] = bi;
    atomicAdd(&ctrl[C_COUNTS + bi], 1);
  }
}

// ------------- setup: aux loss, offsets (NO padding), tile table -------------
__global__ void setup_kern(int* __restrict__ ctrl, float* __restrict__ aux_out)
{
  const int t = threadIdx.x;
  for (int i = t; i < 3072; i += 256) ctrl[C_PERM + i] = -1;
  if (t == 0){
    int off = 0, tc = 0;
    float aux = 0.f;
    for (int e = 0; e < NEXP; e++){
      int c = ctrl[C_COUNTS + e];
      ctrl[C_PADOFF + e] = off;
      ctrl[C_CURSOR + e] = off;
      int nt = (c + BM - 1) / BM;
      for (int j = 0; j < nt; j++){
        ctrl[C_TILE_E   + tc] = e;
        ctrl[C_TILE_M0  + tc] = off + j*BM;
        ctrl[C_TILE_ROWS+ tc] = min(BM, c - j*BM);
        tc++;
      }
      off += c;                                  // tight packing, no padding
      float fr = (float)c * (1.f/(float)N_TOK);
      float d = fr - 1.f/(float)NEXP;
      aux += d*d;
    }
    ctrl[C_TILECNT] = tc;
    *aux_out = aux * (1.f/(float)NEXP);
  }
}

// ------------------------- scatter tokens into grouped slots -----------------
__global__ __launch_bounds__(256) void scatter_kern(int* __restrict__ ctrl)
{
  const int n = blockIdx.x * 256 + threadIdx.x;
  const int e = ctrl[C_EXPERT + n];
  const int pos = atomicAdd(&ctrl[C_CURSOR + e], 1);
  ctrl[C_PERM + pos] = n;
}

// ------------------ gather + f32->bf16 convert of x into Xg ------------------
__global__ __launch_bounds__(256) void xg_kern(
    const float* __restrict__ x, const int* __restrict__ ctrl,
    u16* __restrict__ Xg)
{
  const int slot = blockIdx.x, t = threadIdx.x;
  const int tok = ctrl[C_PERM + slot];
  ushort4 o;
  if (tok >= 0){
    f32x4 v = *(const f32x4*)(x + (size_t)tok*DDIM + t*4);
    o.x = f2bf(v.x); o.y = f2bf(v.y); o.z = f2bf(v.z); o.w = f2bf(v.w);
  } else { o.x = 0; o.y = 0; o.z = 0; o.w = 0; }
  *(ushort4*)(Xg + (size_t)slot*DDIM + t*4) = o;
}

// --------------------------- the two FFN GEMMs -------------------------------
// MODE 1: Hg = gelu(Xg @ w1[e] + b1[e])   K=1024, N=4096, BM=256, BN=128, BK=32
// MODE 2: out[tok] += Hg @ w2[e] + b2[e]  K=4096 split-K x4, same tile geometry
//
// Fat tiles (BM=256,BN=128) cut L2-request redundancy ~2x vs BN=64:
// W requested ~1.05x unique (1 m-tile/expert typ.), A ~x(n-blocks) but A is
// small. m97-proven 2-phase syncthreads loop. B-path rebuilt m97-style:
// coalesced fp32 register loads (issued before COMPUTE, latency hidden),
// cvt_pk once per element, k-contiguous bf16 LDS tile [n][k] with quad-XOR
// swizzle (slot q^((n>>1)&7)); fragments read as 2x ds_read_b64 (k-order
// preserved; ~4-way, cheap). A staged via global_load_lds + chunk-XOR (the
// R2/R5 scheme that measured 0 bank conflicts).
template<int MODE>
__global__ __launch_bounds__(512, 2) void moe_gemm(
    const u16* __restrict__ Ag, const float* __restrict__ W,
    const float* __restrict__ bias, u16* __restrict__ Hg,
    float* __restrict__ outp, const int* __restrict__ ctrl)
{
  constexpr int K    = (MODE==1) ? DDIM : HDIM;   // full reduction dim
  constexpr int NN   = (MODE==1) ? HDIM : DDIM;   // output dim
  constexpr int KS   = (MODE==1) ? 1 : 4;         // split-K factor
  constexpr int KLOC = K / KS;                    // 1024 / 1024
  constexpr int BN   = 128;
  constexpr int BK   = 32;
  constexpr int NT   = KLOC / BK;                 // 32

  const int by = blockIdx.y;
  if (by >= ctrl[C_TILECNT]) return;
  const int e    = ctrl[C_TILE_E + by];
  const int m0   = ctrl[C_TILE_M0 + by];
  const int rows = ctrl[C_TILE_ROWS + by];
  const int n0   = blockIdx.x * BN;
  const int kb   = (MODE==1) ? 0 : blockIdx.z * KLOC;

  const int tid = threadIdx.x;
  const int w = tid >> 6, l = tid & 63;
  const int wr = w >> 1, wc = w & 1;              // 4 x 2 wave grid
  const int lhi = l >> 4, llo = l & 15;

  __shared__ __align__(16) u16 As[2][BM*BK];      // bf16 A tile, 2 x 16 KB
  __shared__ __align__(16) u16 Bs[2][BN*BK];      // bf16 W tile [n][k], 2 x 8 KB
  __shared__ int perm_s[BM];

  if constexpr (MODE == 2){
    if (tid < BM) perm_s[tid] = ctrl[C_PERM + m0 + tid];
  }

  f32x4 acc[4][4];
  #pragma unroll
  for (int mf = 0; mf < 4; mf++)
    #pragma unroll
    for (int nf = 0; nf < 4; nf++) acc[mf][nf] = (f32x4){0.f,0.f,0.f,0.f};

  const u16* Abase = Ag + (size_t)m0 * K;
  // A staging: 2 glds/thread; LDS[row][cs] holds global chunk cs^S(row),
  // S(r) = (r&3) ^ (((r>>2)&1)<<1)  (measured conflict-free in R2/R5)
  int arow[2], apos[2];
  #pragma unroll
  for (int i = 0; i < 2; i++){
    int f = i*512 + tid;
    arow[i] = f >> 2;
    apos[i] = (f & 3) ^ (arow[i] & 3) ^ (((arow[i] >> 2) & 1) << 1);
  }
  // B staging: thread -> column bn, k-octet bkg; 8 coalesced fp32 loads
  const int bn  = tid & 127;
  const int bkg = tid >> 7;                       // 0..3
  const int bsw = (bn >> 1) & 7;                  // write-side quad swizzle
  const float* Wn = W + (size_t)e * K * NN + n0 + bn;
  float wreg[8];

#define STAGE_A(buf, k0) { \
    u16* ad = &As[buf][(w*64)*8]; \
    _Pragma("unroll") \
    for (int i = 0; i < 2; i++) \
      gl_lds16(Abase + (size_t)arow[i]*K + (k0) + apos[i]*8, ad + i*512*8); }

#define BLOAD(k0) { \
    _Pragma("unroll") \
    for (int i = 0; i < 8; i++) \
      wreg[i] = Wn[(size_t)((k0) + bkg*8 + i) * NN]; }

#define BPACK(buf) { \
    u32 p0 = pkbf(wreg[0], wreg[1]), p1 = pkbf(wreg[2], wreg[3]); \
    u32 p2 = pkbf(wreg[4], wreg[5]), p3 = pkbf(wreg[6], wreg[7]); \
    u16* bd = &Bs[buf][bn*BK]; \
    *(u32x2*)&bd[((2*bkg)   ^ bsw) << 2] = (u32x2){p0, p1}; \
    *(u32x2*)&bd[((2*bkg+1) ^ bsw) << 2] = (u32x2){p2, p3}; }

#define COMPUTE(buf) { \
    s16x8 a[4]; \
    _Pragma("unroll") \
    for (int mf = 0; mf < 4; mf++){ \
      int row = wr*64 + mf*16 + llo; \
      int pos = (lhi ^ (row & 3)) ^ (((row >> 2) & 1) << 1); \
      a[mf] = *(const s16x8*)&As[buf][row*BK + pos*8]; } \
    _Pragma("unroll") \
    for (int nf = 0; nf < 4; nf++){ \
      const int col = wc*64 + nf*16 + llo; \
      const int sw = (col >> 1) & 7; \
      const u16* bb = &Bs[buf][col*BK]; \
      union { u32 u[4]; s16x8 v; } bfr; \
      *(u32x2*)&bfr.u[0] = *(const u32x2*)&bb[((2*lhi)   ^ sw) << 2]; \
      *(u32x2*)&bfr.u[2] = *(const u32x2*)&bb[((2*lhi+1) ^ sw) << 2]; \
      _Pragma("unroll") \
      for (int mf = 0; mf < 4; mf++) \
        acc[mf][nf] = __builtin_amdgcn_mfma_f32_16x16x32_bf16(a[mf], bfr.v, acc[mf][nf], 0, 0, 0); \
    } }

  // prologue: fill buffer 0
  BLOAD(kb);
  STAGE_A(0, kb);
  BPACK(0);                    // compiler waits the 8 B-loads here
  __syncthreads();             // drains A glds + publishes B writes

  int cur = 0;
  #pragma unroll 1
  for (int t = 0; t < NT; t++){
    if (t+1 < NT){
      BLOAD(kb + (t+1)*BK);            // issue early: latency hides under COMPUTE
      STAGE_A(cur^1, kb + (t+1)*BK);
    }
    COMPUTE(cur);
    if (t+1 < NT){ BPACK(cur^1); }
    __syncthreads();
    cur ^= 1;
  }

  if constexpr (MODE == 1){
    const float* bp = bias + (size_t)e*NN + n0;
    #pragma unroll
    for (int nf = 0; nf < 4; nf++){
      const int cl = wc*64 + nf*16 + llo;
      const float bb = bp[cl];
      #pragma unroll
      for (int mf = 0; mf < 4; mf++){
        #pragma unroll
        for (int r = 0; r < 4; r++){
          const int rl = wr*64 + mf*16 + lhi*4 + r;
          if (rl < rows){
            float vv = acc[mf][nf][r] + bb;
            float gel = 0.5f * vv * (1.0f + erff(vv * 0.70710678118f)); // exact gelu
            Hg[(size_t)(m0+rl)*NN + n0 + cl] = f2bf(gel);
          }
        }
      }
    }
  } else {
    const float* bp = bias + (size_t)e*NN + n0;
    const bool addb = (blockIdx.z == 0);
    #pragma unroll
    for (int mf = 0; mf < 4; mf++){
      #pragma unroll
      for (int r = 0; r < 4; r++){
        const int rl = wr*64 + mf*16 + lhi*4 + r;
        if (rl < rows){
          const int tok = perm_s[rl];
          #pragma unroll
          for (int nf = 0; nf < 4; nf++){
            const int cl = wc*64 + nf*16 + llo;
            float v = acc[mf][nf][r] + (addb ? bp[cl] : 0.f);
            atomicAdd(&outp[(size_t)tok*DDIM + n0 + cl], v);
          }
        }
      }
    }
  }
#undef STAGE_A
#undef BLOAD
#undef BPACK
#undef COMPUTE
}

extern "C" void kernel_launch(void* const* d_in, const int* in_sizes, int n_in,
                              void* d_out, int out_size, void* d_ws, size_t ws_size,
                              hipStream_t stream)
{
  (void)in_sizes; (void)n_in; (void)out_size; (void)ws_size;
  const float* x  = (const float*)d_in[0];
  const float* gw = (const float*)d_in[1];
  const float* gb = (const float*)d_in[2];
  const float* w1 = (const float*)d_in[3];
  const float* b1 = (const float*)d_in[4];
  const float* w2 = (const float*)d_in[5];
  const float* b2 = (const float*)d_in[6];
  float* out = (float*)d_out;
  char* ws = (char*)d_ws;
  int* ctrl = (int*)ws;
  u16* Xg = (u16*)(ws + XG_OFF);
  u16* Hg = (u16*)(ws + HG_OFF);

  hipMemsetAsync(ctrl, 0, 64, stream);                       // counts
  hipMemsetAsync(out, 0, (size_t)N_TOK*DDIM*4, stream);      // split-K accum base
  gate_kern<<<N_TOK/4, 256, 0, stream>>>(x, gw, gb, ctrl);
  setup_kern<<<1, 256, 0, stream>>>(ctrl, out + (size_t)N_TOK*DDIM);
  scatter_kern<<<N_TOK/256, 256, 0, stream>>>(ctrl);
  xg_kern<<<N_TOK, 256, 0, stream>>>(x, ctrl, Xg);
  moe_gemm<1><<<dim3(HDIM/128, MAXT),    512, 0, stream>>>(Xg, w1, b1, Hg, nullptr, ctrl);
  moe_gemm<2><<<dim3(DDIM/128, MAXT, 4), 512, 0, stream>>>(Hg, w2, b2, nullptr, out, ctrl);
}